// Round 5
// baseline (349.956 us; speedup 1.0000x reference)
//
#include <hip/hip_runtime.h>

// Problem constants (match reference.py)
#define BB 32
#define SS 2048
#define UU 1024
#define NCHUNK 32               // S-chunks per (b); blocks = BB*NCHUNK = 1024
#define SCHUNK (SS / NCHUNK)    // 64 rows per block

// clang ext-vector (NOT HIP_vector_type struct) — required by
// __builtin_nontemporal_load; same 16B layout as float4.
typedef float f32x4 __attribute__((ext_vector_type(4)));

// Kernel 1: init outputs. d_out layout = [context (B*U) | attention (B*S)].
// attention = softmax over a size-1 axis == 1.0 exactly; context starts at 0
// (accumulated by atomics in kernel 2). d_out is re-poisoned to 0xAA before
// every timed launch, so this init must run every call.
__global__ void __launch_bounds__(256) init_out_kernel(float* __restrict__ out) {
    int i = blockIdx.x * blockDim.x + threadIdx.x;   // 0 .. 65535
    if (i < BB * UU) out[i] = 0.0f;                  // context region
    if (i < BB * SS) out[BB * UU + i] = 1.0f;        // attention region
}

// Kernel 2: context[b,u] = sum_s hidden[b,s,u].
// Block = 256 threads, each owns one f32x4 (4 consecutive u's) -> full U row.
// blockIdx encodes (b, s-chunk). Coalesced: 256 threads * 16B = 4KB/iter.
// 1024 blocks = 16 waves/CU for latency hiding; 32-way atomic contention
// per context address (1M atomics total, negligible vs 268 MB stream).
// Loads are nontemporal: single-use 268 MB stream > 256 MiB L3, no reuse.
__global__ void __launch_bounds__(256) rowsum_kernel(const float* __restrict__ h,
                                                     float* __restrict__ out) {
    const int tid = threadIdx.x;                     // 0..255
    const int b   = blockIdx.x >> 5;                 // / NCHUNK
    const int c   = blockIdx.x & (NCHUNK - 1);       // % NCHUNK

    const f32x4* p = reinterpret_cast<const f32x4*>(h)
                   + ((size_t)b * SS + (size_t)c * SCHUNK) * (UU / 4) + tid;

    f32x4 acc = {0.f, 0.f, 0.f, 0.f};
    #pragma unroll 8
    for (int s = 0; s < SCHUNK; ++s) {
        f32x4 v = __builtin_nontemporal_load(&p[(size_t)s * (UU / 4)]);
        acc += v;
    }

    float* ctx = out + (size_t)b * UU + (size_t)tid * 4;
    atomicAdd(ctx + 0, acc.x);
    atomicAdd(ctx + 1, acc.y);
    atomicAdd(ctx + 2, acc.z);
    atomicAdd(ctx + 3, acc.w);
}

extern "C" void kernel_launch(void* const* d_in, const int* in_sizes, int n_in,
                              void* d_out, int out_size, void* d_ws, size_t ws_size,
                              hipStream_t stream) {
    // Input order: s_prev, hidden_states, Ww, Wb, Uw, Ub, Vw, Vb (all fp32).
    const float* hidden = (const float*)d_in[1];
    float* out = (float*)d_out;

    // Init: 65536 threads cover both regions (context 32768, attention 65536).
    init_out_kernel<<<(BB * SS) / 256, 256, 0, stream>>>(out);

    // Reduction over S.
    rowsum_kernel<<<BB * NCHUNK, 256, 0, stream>>>(hidden, out);
}